// Round 1
// 871.854 us; speedup vs baseline: 1.0065x; 1.0065x over previous
//
#include <hip/hip_runtime.h>
#include <math.h>

#define B_ 128
#define D_ 4096
#define V_ 32000

#define BN 64
#define BK 32
#define KSTEPS (D_ / BK)                    // 128
#define ASTEP_BYTES (128 * BK * 2 * 2)      // 16384 B per K-step A image (2 fp16 splits)
#define ASTEP_SHORTS (ASTEP_BYTES / 2)      // 8192
#define WS_LDS_BYTES (2 * 4 * 4 * 16 * 16)  // 8192 B W fragment image (2 splits)
#define WS_LDS_OFF ASTEP_BYTES

// Exact power-of-2 scaling keeps fp16 split residuals out of denormal range.
// A is pre-scaled by 2^8, W by 2^12; epilogue descales by 2^-20.
#define SCALE_A 256.0f
#define SCALE_W 4096.0f
#define DESCALE 9.5367431640625e-7f  // 2^-20

typedef __attribute__((ext_vector_type(8))) short short8;
typedef __attribute__((ext_vector_type(8))) _Float16 half8;
typedef __attribute__((ext_vector_type(4))) float floatx4;

// ---------------- threefry2x32, key = (0, 42), JAX partitionable ------------
__device__ __forceinline__ void threefry2x32_0_42(unsigned& x0, unsigned& x1) {
  const unsigned k0 = 0u;
  const unsigned k1 = 42u;
  const unsigned k2 = 0u ^ 42u ^ 0x1BD11BDAu;
  x0 += k0; x1 += k1;
#define TF_R(r) { x0 += x1; x1 = (x1 << (r)) | (x1 >> (32 - (r))); x1 ^= x0; }
#define TF_G0 TF_R(13) TF_R(15) TF_R(26) TF_R(6)
#define TF_G1 TF_R(17) TF_R(29) TF_R(16) TF_R(24)
  TF_G0; x0 += k1; x1 += k2 + 1u;
  TF_G1; x0 += k2; x1 += k0 + 2u;
  TF_G0; x0 += k0; x1 += k1 + 3u;
  TF_G1; x0 += k1; x1 += k2 + 4u;
  TF_G0; x0 += k2; x1 += k0 + 5u;
#undef TF_G1
#undef TF_G0
#undef TF_R
}

__device__ __forceinline__ float gumbel_from_bits(unsigned bits) {
  float f = __uint_as_float((bits >> 9) | 0x3F800000u) - 1.0f;
  float u = fmaxf(f, 1.17549435e-38f);
  return -logf(-logf(u));
}

// ---------------- kernel 0: pre-split A (x*2^8 -> fp16 h0+h1) ---------------
// Image layout per step: offset(s,mt,quad,m) = (((s*8+mt)*4+quad)*16+m)*16B,
// holding (A*256)_s[mt*16+m][step*32 + quad*8 .. +8] as 8 fp16.
__global__ __launch_bounds__(256) void asplit_kernel(const float* __restrict__ A,
                                                     unsigned short* __restrict__ Asp) {
  const int t = blockIdx.x * 256 + threadIdx.x;  // 0..65535
  const int m_glob = t >> 9;                     // 0..127
  const int koct = t & 511;                      // 0..511 (8-elem groups)
  const int sk = koct >> 2, quad = koct & 3;
  const int mt = m_glob >> 4, ml = m_glob & 15;
  const float* src = A + (size_t)m_glob * D_ + koct * 8;
  half8 h0, h1;
#pragma unroll
  for (int kk = 0; kk < 8; kk++) {
    const float x = src[kk] * SCALE_A;
    const _Float16 a0 = (_Float16)x;       // RNE
    const float r1 = x - (float)a0;        // exact
    const _Float16 a1 = (_Float16)r1;      // captures bits 11..22 (+RNE)
    h0[kk] = a0; h1[kk] = a1;
  }
  unsigned short* dst = Asp + (size_t)sk * ASTEP_SHORTS;
  const int base = ((mt * 4 + quad) * 16 + ml) * 8;     // shorts, s=0
  const int sstride = 8 * 4 * 16 * 8;                   // 4096 shorts per split
  *(half8*)(dst + base) = h0;
  *(half8*)(dst + base + sstride) = h1;
}

// ---------------- kernel 1: fp16x4 MFMA GEMM  L[b][v] = (A.W^T)/temp --------
// block tile 128(m) x 64(n), BK=32, 4 waves each 64x32 (4 mt x 2 nt).
__global__ __launch_bounds__(256) void gemm_mfma(const unsigned short* __restrict__ Asp,
                                                 const float* __restrict__ W,
                                                 const float* __restrict__ temp,
                                                 float* __restrict__ L) {
  __shared__ unsigned char lds[ASTEP_BYTES + WS_LDS_BYTES];  // 24576 B
  const int tid = threadIdx.x;
  const int vblock = blockIdx.x * BN;
  const int wave = tid >> 6, lane = tid & 63;
  const int quad = lane >> 4, ml = lane & 15;
  const int wm = wave >> 1, wn = wave & 1;

  // W staging role: thread -> (v row, k octet)
  const int wv = tid >> 2;                 // 0..63
  const int wko = tid & 3;                 // quad of k
  const float* wsrc = W + (size_t)(vblock + wv) * D_ + wko * 8;
  const int wnt = wv >> 4, wvl = wv & 15;
  const int wbase0 = WS_LDS_OFF + (((0 * 4 + wnt) * 4 + wko) * 16 + wvl) * 16;
  const int wsstride = 4 * 4 * 16 * 16;    // 4096 B per split

  floatx4 acc[4][2];
#pragma unroll
  for (int i = 0; i < 4; i++)
#pragma unroll
    for (int j = 0; j < 2; j++) acc[i][j] = (floatx4){0.f, 0.f, 0.f, 0.f};

  // prologue: preload W regs for step 0
  float4 wa = *(const float4*)(wsrc);
  float4 wb = *(const float4*)(wsrc + 4);

  for (int st = 0; st < KSTEPS; st++) {
    __syncthreads();
    // --- A: async global -> LDS (pre-split image, contiguous) ---
    const unsigned char* abase = (const unsigned char*)(Asp + (size_t)st * ASTEP_SHORTS);
#pragma unroll
    for (int i = 0; i < 4; i++) {
      const int off = (i * 256 + tid) * 16;
      __builtin_amdgcn_global_load_lds(
          (const __attribute__((address_space(1))) unsigned int*)(abase + off),
          (__attribute__((address_space(3))) unsigned int*)(&lds[off]), 16, 0, 0);
    }
    // --- W: split current regs (fp32 -> 2 fp16), write fragment LDS ---
    {
      const float x[8] = {wa.x, wa.y, wa.z, wa.w, wb.x, wb.y, wb.z, wb.w};
      half8 w0, w1;
#pragma unroll
      for (int kk = 0; kk < 8; kk++) {
        const float xs = x[kk] * SCALE_W;
        const _Float16 b0 = (_Float16)xs;
        const float r1 = xs - (float)b0;
        const _Float16 b1 = (_Float16)r1;
        w0[kk] = b0; w1[kk] = b1;
      }
      *(half8*)(&lds[wbase0]) = w0;
      *(half8*)(&lds[wbase0 + wsstride]) = w1;
    }
    // --- prefetch next step's W regs (latency hides under MFMA below) ---
    {
      const int stn = (st + 1 < KSTEPS) ? st + 1 : st;
      const float* wp = wsrc + (size_t)stn * BK;
      wa = *(const float4*)(wp);
      wb = *(const float4*)(wp + 4);
    }
    __syncthreads();

    // --- fragments ---
    half8 af[2][4];
#pragma unroll
    for (int s = 0; s < 2; s++)
#pragma unroll
      for (int i = 0; i < 4; i++) {
        const int mt = wm * 4 + i;
        af[s][i] = *(const half8*)(&lds[(((s * 8 + mt) * 4 + quad) * 16 + ml) * 16]);
      }
    half8 wf[2][2];
#pragma unroll
    for (int s = 0; s < 2; s++)
#pragma unroll
      for (int j = 0; j < 2; j++) {
        const int nt = wn * 2 + j;
        wf[s][j] = *(const half8*)(&lds[WS_LDS_OFF + (((s * 4 + nt) * 4 + quad) * 16 + ml) * 16]);
      }

    // --- 4-product split MFMA: (0,0) (0,1) (1,0) (1,1) ---
#pragma unroll
    for (int i = 0; i < 4; i++)
#pragma unroll
      for (int j = 0; j < 2; j++) {
        acc[i][j] = __builtin_amdgcn_mfma_f32_16x16x32_f16(af[0][i], wf[0][j], acc[i][j], 0, 0, 0);
        acc[i][j] = __builtin_amdgcn_mfma_f32_16x16x32_f16(af[0][i], wf[1][j], acc[i][j], 0, 0, 0);
        acc[i][j] = __builtin_amdgcn_mfma_f32_16x16x32_f16(af[1][i], wf[0][j], acc[i][j], 0, 0, 0);
        acc[i][j] = __builtin_amdgcn_mfma_f32_16x16x32_f16(af[1][i], wf[1][j], acc[i][j], 0, 0, 0);
      }
  }

  // --- epilogue: C/D layout col=lane&15, row=(lane>>4)*4+reg; descale 2^-20 --
#pragma unroll
  for (int i = 0; i < 4; i++)
#pragma unroll
    for (int j = 0; j < 2; j++) {
      const int col = vblock + (wn * 2 + j) * 16 + ml;
#pragma unroll
      for (int r = 0; r < 4; r++) {
        const int row = wm * 64 + i * 16 + quad * 4 + r;
        L[(size_t)row * V_ + col] = acc[i][j][r] * (DESCALE / temp[row]);
      }
    }
}

// ---------------- fused top-p + gumbel sampler (1 block = 1 row) ------------
#define NBINS 8192
#define SHIFT 17
#define CAP 2048

__device__ __forceinline__ float blockSum1024(float x, float* redf) {
#pragma unroll
  for (int o = 32; o > 0; o >>= 1) x += __shfl_down(x, o);
  const int w = threadIdx.x >> 6;
  __syncthreads();
  if ((threadIdx.x & 63) == 0) redf[w] = x;
  __syncthreads();
  if (threadIdx.x == 0) {
    float t = redf[0];
    for (int k = 1; k < 16; k++) t += redf[k];
    redf[16] = t;
  }
  __syncthreads();
  return redf[16];
}

__device__ __forceinline__ float blockMax1024(float x, float* redf) {
#pragma unroll
  for (int o = 32; o > 0; o >>= 1) x = fmaxf(x, __shfl_down(x, o));
  const int w = threadIdx.x >> 6;
  __syncthreads();
  if ((threadIdx.x & 63) == 0) redf[w] = x;
  __syncthreads();
  if (threadIdx.x == 0) {
    float t = redf[0];
    for (int k = 1; k < 16; k++) t = fmaxf(t, redf[k]);
    redf[16] = t;
  }
  __syncthreads();
  return redf[16];
}

__global__ __launch_bounds__(1024) void sampler_kernel(const float* __restrict__ L,
                                                       const float* __restrict__ top_p,
                                                       int* __restrict__ out) {
  __shared__ float hist[NBINS];     // 32 KB
  __shared__ float listE[CAP];      // 8 KB
  __shared__ int cnt;
  __shared__ float redf[20];
  __shared__ int redi[16];
  const int b = blockIdx.x, tid = threadIdx.x;
  const float* l = L + (size_t)b * V_;

  for (int i = tid; i < NBINS; i += 1024) hist[i] = 0.f;
  if (tid == 0) cnt = 0;
  __syncthreads();

  // pass 1: row max
  float mx = -INFINITY;
  for (int v = tid; v < V_; v += 1024) mx = fmaxf(mx, l[v]);
  mx = blockMax1024(mx, redf);

  // pass 2: S + histogram of e = exp(l - m) on float-bit bins
  float s = 0.f;
  for (int v = tid; v < V_; v += 1024) {
    const float e = expf(l[v] - mx);
    s += e;
    unsigned bin = __float_as_uint(e) >> SHIFT;   // e in (0,1] -> bin <= 8128
    if (bin >= NBINS) bin = NBINS - 1;
    atomicAdd(&hist[bin], e);
  }
  const float S = blockSum1024(s, redf);  // barrier inside also orders hist atomics
  const float ps = top_p[b] * S;

  // binary search: minimal beta with cumAbove(beta) = sum_{bins > beta} <= ps
  int lo = -1, hi = NBINS - 1;
  while (hi - lo > 1) {
    const int mid = (lo + hi) >> 1;
    float a = 0.f;
    for (int i = tid; i < NBINS; i += 1024)
      if (i > mid) a += hist[i];
    a = blockSum1024(a, redf);
    if (a <= ps) hi = mid; else lo = mid;
  }
  const int beta = hi;
  float cumAbove;
  {
    float a = 0.f;
    for (int i = tid; i < NBINS; i += 1024)
      if (i > beta) a += hist[i];
    cumAbove = blockSum1024(a, redf);
  }

  // collect boundary-bin tokens
  for (int v = tid; v < V_; v += 1024) {
    const float e = expf(l[v] - mx);
    unsigned bin = __float_as_uint(e) >> SHIFT;
    if (bin >= NBINS) bin = NBINS - 1;
    if ((int)bin == beta) {
      const int p = atomicAdd(&cnt, 1);
      if (p < CAP) listE[p] = e;
    }
  }
  __syncthreads();
  const int n = cnt;

  // refine cutoff c within bin beta:  kept <=> bits(e) >= c
  long long blo = ((long long)beta << SHIFT) - 1;
  long long bhi = ((long long)(beta + 1)) << SHIFT;
  if (n <= CAP) {
    while (bhi - blo > 1) {
      const long long mid = (blo + bhi) >> 1;
      const float t = __uint_as_float((unsigned)mid);
      float a = 0.f;
      for (int i = tid; i < n; i += 1024) {
        const float e = listE[i];
        if (e > t) a += e;
      }
      a = cumAbove + blockSum1024(a, redf);
      if (a <= ps) bhi = mid; else blo = mid;
    }
  } else {  // rare overflow fallback: full-row predicate
    while (bhi - blo > 1) {
      const long long mid = (blo + bhi) >> 1;
      const float t = __uint_as_float((unsigned)mid);
      float a = 0.f;
      for (int v = tid; v < V_; v += 1024) {
        const float e = expf(l[v] - mx);
        unsigned bin = __float_as_uint(e) >> SHIFT;
        if (bin >= NBINS) bin = NBINS - 1;
        if ((int)bin == beta && e > t) a += e;
      }
      a = cumAbove + blockSum1024(a, redf);
      if (a <= ps) bhi = mid; else blo = mid;
    }
  }
  const unsigned c = (unsigned)bhi;

  // final pass: gumbel-argmax over kept tokens (JAX partitionable threefry)
  float best = -INFINITY;
  int bi = 0x7FFFFFFF;
  for (int v = tid; v < V_; v += 1024) {
    const float lv = l[v];
    const float e = expf(lv - mx);
    if (__float_as_uint(e) >= c) {
      unsigned x0 = 0u, x1 = (unsigned)(b * V_ + v);
      threefry2x32_0_42(x0, x1);
      const float sc = lv + gumbel_from_bits(x0 ^ x1);
      if (sc > best) { best = sc; bi = v; }
    }
  }
#pragma unroll
  for (int o = 32; o > 0; o >>= 1) {
    const float t = __shfl_down(best, o);
    const int j = __shfl_down(bi, o);
    if (t > best || (t == best && j < bi)) { best = t; bi = j; }
  }
  const int w = tid >> 6;
  __syncthreads();
  if ((tid & 63) == 0) { redf[w] = best; redi[w] = bi; }
  __syncthreads();
  if (tid == 0) {
    float bs = redf[0];
    int bidx = redi[0];
    for (int k = 1; k < 16; k++)
      if (redf[k] > bs || (redf[k] == bs && redi[k] < bidx)) { bs = redf[k]; bidx = redi[k]; }
    out[b] = bidx;
  }
}

extern "C" void kernel_launch(void* const* d_in, const int* in_sizes, int n_in,
                              void* d_out, int out_size, void* d_ws, size_t ws_size,
                              hipStream_t stream) {
  (void)in_sizes; (void)n_in; (void)out_size; (void)ws_size;
  const float* A = (const float*)d_in[0];     // hidden_states [128,4096]
  const float* W = (const float*)d_in[1];     // embd_weight   [32000,4096]
  const float* temp = (const float*)d_in[2];  // temperature   [128]
  const float* topp = (const float*)d_in[3];  // top_p         [128]
  int* out = (int*)d_out;                     // ids           [128] int32

  char* base = (char*)d_ws;
  float* L = (float*)base;                                  // 16,384,000 B
  unsigned short* Asp = (unsigned short*)(base + (size_t)B_ * V_ * 4);  // 2,097,152 B

  asplit_kernel<<<dim3(256), dim3(256), 0, stream>>>(A, Asp);
  gemm_mfma<<<dim3(V_ / BN), dim3(256), 0, stream>>>(Asp, W, temp, L);
  sampler_kernel<<<dim3(B_), dim3(1024), 0, stream>>>(L, topp, out);
}

// Round 3
// 815.294 us; speedup vs baseline: 1.0764x; 1.0694x over previous
//
#include <hip/hip_runtime.h>
#include <math.h>

#define B_ 128
#define D_ 4096
#define V_ 32000

#define BN 64
#define BK 32
#define KSTEPS (D_ / BK)                    // 128
#define ASTEP_BYTES (128 * BK * 2 * 2)      // 16384 B per K-step A image (2 fp16 splits)
#define ASTEP_SHORTS (ASTEP_BYTES / 2)      // 8192
#define WS_LDS_BYTES (2 * 4 * 4 * 16 * 16)  // 8192 B W fragment image (2 splits)
#define WS_LDS_OFF ASTEP_BYTES
#define BUF_STRIDE (ASTEP_BYTES + WS_LDS_BYTES)  // 24576 B per pipeline buffer

// Exact power-of-2 scaling keeps fp16 split residuals out of denormal range.
// A is pre-scaled by 2^8, W by 2^12; epilogue descales by 2^-20.
#define SCALE_A 256.0f
#define SCALE_W 4096.0f
#define DESCALE 9.5367431640625e-7f  // 2^-20

typedef __attribute__((ext_vector_type(8))) _Float16 half8;
typedef __attribute__((ext_vector_type(4))) float floatx4;

#define MFMA16(a, b, c) __builtin_amdgcn_mfma_f32_16x16x32_f16((a), (b), (c), 0, 0, 0)

// ---------------- threefry2x32, key = (0, 42), JAX partitionable ------------
__device__ __forceinline__ void threefry2x32_0_42(unsigned& x0, unsigned& x1) {
  const unsigned k0 = 0u;
  const unsigned k1 = 42u;
  const unsigned k2 = 0u ^ 42u ^ 0x1BD11BDAu;
  x0 += k0; x1 += k1;
#define TF_R(r) { x0 += x1; x1 = (x1 << (r)) | (x1 >> (32 - (r))); x1 ^= x0; }
#define TF_G0 TF_R(13) TF_R(15) TF_R(26) TF_R(6)
#define TF_G1 TF_R(17) TF_R(29) TF_R(16) TF_R(24)
  TF_G0; x0 += k1; x1 += k2 + 1u;
  TF_G1; x0 += k2; x1 += k0 + 2u;
  TF_G0; x0 += k0; x1 += k1 + 3u;
  TF_G1; x0 += k1; x1 += k2 + 4u;
  TF_G0; x0 += k2; x1 += k0 + 5u;
#undef TF_G1
#undef TF_G0
#undef TF_R
}

__device__ __forceinline__ float gumbel_from_bits(unsigned bits) {
  float f = __uint_as_float((bits >> 9) | 0x3F800000u) - 1.0f;
  float u = fmaxf(f, 1.17549435e-38f);
  return -logf(-logf(u));
}

// ---------------- kernel 0: pre-split A (x*2^8 -> fp16 h0+h1) ---------------
// Image layout per step: offset(s,mt,quad,m) = (((s*8+mt)*4+quad)*16+m)*16B,
// holding (A*256)_s[mt*16+m][step*32 + quad*8 .. +8] as 8 fp16.
__global__ __launch_bounds__(256) void asplit_kernel(const float* __restrict__ A,
                                                     unsigned short* __restrict__ Asp) {
  const int t = blockIdx.x * 256 + threadIdx.x;  // 0..65535
  const int m_glob = t >> 9;                     // 0..127
  const int koct = t & 511;                      // 0..511 (8-elem groups)
  const int sk = koct >> 2, quad = koct & 3;
  const int mt = m_glob >> 4, ml = m_glob & 15;
  const float* src = A + (size_t)m_glob * D_ + koct * 8;
  half8 h0, h1;
#pragma unroll
  for (int kk = 0; kk < 8; kk++) {
    const float x = src[kk] * SCALE_A;
    const _Float16 a0 = (_Float16)x;       // RNE
    const float r1 = x - (float)a0;        // exact
    const _Float16 a1 = (_Float16)r1;      // captures bits 11..22 (+RNE)
    h0[kk] = a0; h1[kk] = a1;
  }
  unsigned short* dst = Asp + (size_t)sk * ASTEP_SHORTS;
  const int base = ((mt * 4 + quad) * 16 + ml) * 8;     // shorts, s=0
  const int sstride = 8 * 4 * 16 * 8;                   // 4096 shorts per split
  *(half8*)(dst + base) = h0;
  *(half8*)(dst + base + sstride) = h1;
}

// ---------------- kernel 1: fp16x4 MFMA GEMM  L[b][v] = (A.W^T)/temp --------
// block tile 128(m) x 64(n), BK=32, 4 waves each 64x32 (4 mt x 2 nt).
// Double-buffered 2-phase pipeline with __syncthreads() step barriers:
// step t computes buf[cur] while A[t+1] (global_load_lds) and W[t+1] (regs,
// loaded at step t-1) are staged into buf[nxt]; W[t+2] regs prefetched at the
// top of the step. __syncthreads() = fence + vmcnt(0)/lgkmcnt(0) drain, so no
// cross-wave ordering assumptions are made (round-2's raw-s_barrier race fix).
__global__ __launch_bounds__(256) void gemm_mfma(const unsigned short* __restrict__ Asp,
                                                 const float* __restrict__ W,
                                                 const float* __restrict__ temp,
                                                 float* __restrict__ L) {
  __shared__ unsigned char lds[2 * BUF_STRIDE];  // 49152 B
  const int tid = threadIdx.x;
  const int vblock = blockIdx.x * BN;
  const int wave = tid >> 6, lane = tid & 63;
  const int quad = lane >> 4, ml = lane & 15;
  const int wm = wave >> 1, wn = wave & 1;

  // W staging role: thread -> (v row, k octet)
  const int wv = tid >> 2;                 // 0..63
  const int wko = tid & 3;                 // quad of k
  const float* wsrc = W + (size_t)(vblock + wv) * D_ + wko * 8;
  const int wnt = wv >> 4, wvl = wv & 15;
  const int wbase0 = WS_LDS_OFF + ((wnt * 4 + wko) * 16 + wvl) * 16;
  const int wsstride = 4 * 4 * 16 * 16;    // 4096 B per split

  floatx4 acc[4][2];
#pragma unroll
  for (int i = 0; i < 4; i++)
#pragma unroll
    for (int j = 0; j < 2; j++) acc[i][j] = (floatx4){0.f, 0.f, 0.f, 0.f};

// split W regs (WA,WB) -> 2 fp16 images, ds_write into buffer BUFN_
#define WSPLIT_STORE(WA, WB, BUFN_)                                            \
  {                                                                            \
    const float x[8] = {WA.x, WA.y, WA.z, WA.w, WB.x, WB.y, WB.z, WB.w};       \
    half8 w0, w1;                                                              \
    _Pragma("unroll") for (int kk = 0; kk < 8; kk++) {                         \
      const float xs = x[kk] * SCALE_W;                                        \
      const _Float16 b0 = (_Float16)xs;                                        \
      const float r1 = xs - (float)b0;                                         \
      w0[kk] = b0; w1[kk] = (_Float16)r1;                                      \
    }                                                                          \
    *(half8*)(&lds[(BUFN_)*BUF_STRIDE + wbase0]) = w0;                         \
    *(half8*)(&lds[(BUFN_)*BUF_STRIDE + wbase0 + wsstride]) = w1;              \
  }

// ds_read fragments from buffer BUFC_ and run the 4-product MFMA group
#define COMPUTE(BUFC_)                                                         \
  {                                                                            \
    half8 af[2][4];                                                            \
    _Pragma("unroll") for (int s = 0; s < 2; s++)                              \
    _Pragma("unroll") for (int i = 0; i < 4; i++) {                            \
      const int mt = wm * 4 + i;                                               \
      af[s][i] = *(const half8*)(&lds[(BUFC_)*BUF_STRIDE +                     \
                    (((s * 8 + mt) * 4 + quad) * 16 + ml) * 16]);              \
    }                                                                          \
    half8 wf[2][2];                                                            \
    _Pragma("unroll") for (int s = 0; s < 2; s++)                              \
    _Pragma("unroll") for (int j = 0; j < 2; j++) {                            \
      const int nt = wn * 2 + j;                                               \
      wf[s][j] = *(const half8*)(&lds[(BUFC_)*BUF_STRIDE + WS_LDS_OFF +        \
                    (((s * 4 + nt) * 4 + quad) * 16 + ml) * 16]);              \
    }                                                                          \
    _Pragma("unroll") for (int i = 0; i < 4; i++)                              \
    _Pragma("unroll") for (int j = 0; j < 2; j++) {                            \
      acc[i][j] = MFMA16(af[0][i], wf[0][j], acc[i][j]);                       \
      acc[i][j] = MFMA16(af[0][i], wf[1][j], acc[i][j]);                       \
      acc[i][j] = MFMA16(af[1][i], wf[0][j], acc[i][j]);                       \
      acc[i][j] = MFMA16(af[1][i], wf[1][j], acc[i][j]);                       \
    }                                                                          \
  }

// one pipeline step: compute buf[BUFC_], stage step TSTAGE into buf[BUFN_]
// using W regs (WCA,WCB)=W[TSTAGE]; prefetch W[TPREF] into (WNA,WNB).
#define GSTEP(BUFC_, BUFN_, WCA, WCB, WNA, WNB, TSTAGE, TPREF, DO_PREF)        \
  {                                                                            \
    const unsigned char* abase =                                               \
        (const unsigned char*)(Asp + (size_t)(TSTAGE) * ASTEP_SHORTS);         \
    _Pragma("unroll") for (int i = 0; i < 4; i++) {                            \
      const int off = (i * 256 + tid) * 16;                                    \
      __builtin_amdgcn_global_load_lds(                                        \
          (const __attribute__((address_space(1))) unsigned int*)(abase + off),\
          (__attribute__((address_space(3))) unsigned int*)(                   \
              &lds[(BUFN_)*BUF_STRIDE + off]), 16, 0, 0);                      \
    }                                                                          \
    if (DO_PREF) {                                                             \
      const float* wp = wsrc + (size_t)(TPREF) * BK;                           \
      WNA = *(const float4*)(wp);                                              \
      WNB = *(const float4*)(wp + 4);                                          \
    }                                                                          \
    WSPLIT_STORE(WCA, WCB, BUFN_);                                             \
    COMPUTE(BUFC_);                                                            \
    __syncthreads();                                                           \
  }

  // ---- prologue: stage step 0 into buf0; load W[1] into (wa0,wb0) ----
  float4 wa0 = *(const float4*)(wsrc);       // W[0]
  float4 wb0 = *(const float4*)(wsrc + 4);
  float4 wa1, wb1;
  {
    const unsigned char* abase = (const unsigned char*)Asp;  // step 0
#pragma unroll
    for (int i = 0; i < 4; i++) {
      const int off = (i * 256 + tid) * 16;
      __builtin_amdgcn_global_load_lds(
          (const __attribute__((address_space(1))) unsigned int*)(abase + off),
          (__attribute__((address_space(3))) unsigned int*)(&lds[off]), 16, 0, 0);
    }
    WSPLIT_STORE(wa0, wb0, 0);
    // preload W[1]
    wa0 = *(const float4*)(wsrc + BK);
    wb0 = *(const float4*)(wsrc + BK + 4);
  }
  __syncthreads();

  // ---- main loop: 63 pairs covering compute steps t = 0..125 ----
  for (int t2 = 0; t2 < 63; t2++) {
    const int t = 2 * t2;
    // even: compute buf0 (step t), stage t+1 -> buf1 with (wa0,wb0)=W[t+1],
    //       prefetch W[t+2] -> (wa1,wb1)
    GSTEP(0, 1, wa0, wb0, wa1, wb1, t + 1, t + 2, 1);
    // odd: compute buf1 (step t+1), stage t+2 -> buf0 with (wa1,wb1)=W[t+2],
    //      prefetch W[t+3] -> (wa0,wb0)
    GSTEP(1, 0, wa1, wb1, wa0, wb0, t + 2, t + 3, 1);
  }
  // step 126: compute buf0, stage 127 -> buf1 with (wa0,wb0)=W[127]; no pref
  GSTEP(0, 1, wa0, wb0, wa1, wb1, 127, 127, 0);
  // step 127: compute buf1 (no staging)
  COMPUTE(1);
#undef GSTEP
#undef COMPUTE
#undef WSPLIT_STORE

  // --- epilogue: C/D layout col=lane&15, row=(lane>>4)*4+reg; descale 2^-20 --
#pragma unroll
  for (int i = 0; i < 4; i++)
#pragma unroll
    for (int j = 0; j < 2; j++) {
      const int col = vblock + (wn * 2 + j) * 16 + ml;
#pragma unroll
      for (int r = 0; r < 4; r++) {
        const int row = wm * 64 + i * 16 + quad * 4 + r;
        L[(size_t)row * V_ + col] = acc[i][j][r] * (DESCALE / temp[row]);
      }
    }
}

// ---------------- fused top-p + gumbel sampler (1 block = 1 row) ------------
#define NBINS 8192
#define SHIFT 17
#define CAP 2048

__device__ __forceinline__ float blockSum1024(float x, float* redf) {
#pragma unroll
  for (int o = 32; o > 0; o >>= 1) x += __shfl_down(x, o);
  const int w = threadIdx.x >> 6;
  __syncthreads();
  if ((threadIdx.x & 63) == 0) redf[w] = x;
  __syncthreads();
  if (threadIdx.x == 0) {
    float t = redf[0];
    for (int k = 1; k < 16; k++) t += redf[k];
    redf[16] = t;
  }
  __syncthreads();
  return redf[16];
}

__device__ __forceinline__ float blockMax1024(float x, float* redf) {
#pragma unroll
  for (int o = 32; o > 0; o >>= 1) x = fmaxf(x, __shfl_down(x, o));
  const int w = threadIdx.x >> 6;
  __syncthreads();
  if ((threadIdx.x & 63) == 0) redf[w] = x;
  __syncthreads();
  if (threadIdx.x == 0) {
    float t = redf[0];
    for (int k = 1; k < 16; k++) t = fmaxf(t, redf[k]);
    redf[16] = t;
  }
  __syncthreads();
  return redf[16];
}

__global__ __launch_bounds__(1024) void sampler_kernel(const float* __restrict__ L,
                                                       const float* __restrict__ top_p,
                                                       int* __restrict__ out) {
  __shared__ float hist[NBINS];     // 32 KB
  __shared__ float listE[CAP];      // 8 KB
  __shared__ int cnt;
  __shared__ float redf[20];
  __shared__ int redi[16];
  const int b = blockIdx.x, tid = threadIdx.x;
  const float* l = L + (size_t)b * V_;

  for (int i = tid; i < NBINS; i += 1024) hist[i] = 0.f;
  if (tid == 0) cnt = 0;
  __syncthreads();

  // pass 1: row max
  float mx = -INFINITY;
  for (int v = tid; v < V_; v += 1024) mx = fmaxf(mx, l[v]);
  mx = blockMax1024(mx, redf);

  // pass 2: S + histogram of e = exp(l - m) on float-bit bins
  float s = 0.f;
  for (int v = tid; v < V_; v += 1024) {
    const float e = expf(l[v] - mx);
    s += e;
    unsigned bin = __float_as_uint(e) >> SHIFT;   // e in (0,1] -> bin <= 8128
    if (bin >= NBINS) bin = NBINS - 1;
    atomicAdd(&hist[bin], e);
  }
  const float S = blockSum1024(s, redf);  // barrier inside also orders hist atomics
  const float ps = top_p[b] * S;

  // binary search: minimal beta with cumAbove(beta) = sum_{bins > beta} <= ps
  int lo = -1, hi = NBINS - 1;
  while (hi - lo > 1) {
    const int mid = (lo + hi) >> 1;
    float a = 0.f;
    for (int i = tid; i < NBINS; i += 1024)
      if (i > mid) a += hist[i];
    a = blockSum1024(a, redf);
    if (a <= ps) hi = mid; else lo = mid;
  }
  const int beta = hi;
  float cumAbove;
  {
    float a = 0.f;
    for (int i = tid; i < NBINS; i += 1024)
      if (i > beta) a += hist[i];
    cumAbove = blockSum1024(a, redf);
  }

  // collect boundary-bin tokens
  for (int v = tid; v < V_; v += 1024) {
    const float e = expf(l[v] - mx);
    unsigned bin = __float_as_uint(e) >> SHIFT;
    if (bin >= NBINS) bin = NBINS - 1;
    if ((int)bin == beta) {
      const int p = atomicAdd(&cnt, 1);
      if (p < CAP) listE[p] = e;
    }
  }
  __syncthreads();
  const int n = cnt;

  // refine cutoff c within bin beta:  kept <=> bits(e) >= c
  long long blo = ((long long)beta << SHIFT) - 1;
  long long bhi = ((long long)(beta + 1)) << SHIFT;
  if (n <= CAP) {
    while (bhi - blo > 1) {
      const long long mid = (blo + bhi) >> 1;
      const float t = __uint_as_float((unsigned)mid);
      float a = 0.f;
      for (int i = tid; i < n; i += 1024) {
        const float e = listE[i];
        if (e > t) a += e;
      }
      a = cumAbove + blockSum1024(a, redf);
      if (a <= ps) bhi = mid; else blo = mid;
    }
  } else {  // rare overflow fallback: full-row predicate
    while (bhi - blo > 1) {
      const long long mid = (blo + bhi) >> 1;
      const float t = __uint_as_float((unsigned)mid);
      float a = 0.f;
      for (int v = tid; v < V_; v += 1024) {
        const float e = expf(l[v] - mx);
        unsigned bin = __float_as_uint(e) >> SHIFT;
        if (bin >= NBINS) bin = NBINS - 1;
        if ((int)bin == beta && e > t) a += e;
      }
      a = cumAbove + blockSum1024(a, redf);
      if (a <= ps) bhi = mid; else blo = mid;
    }
  }
  const unsigned c = (unsigned)bhi;

  // final pass: gumbel-argmax over kept tokens (JAX partitionable threefry)
  float best = -INFINITY;
  int bi = 0x7FFFFFFF;
  for (int v = tid; v < V_; v += 1024) {
    const float lv = l[v];
    const float e = expf(lv - mx);
    if (__float_as_uint(e) >= c) {
      unsigned x0 = 0u, x1 = (unsigned)(b * V_ + v);
      threefry2x32_0_42(x0, x1);
      const float sc = lv + gumbel_from_bits(x0 ^ x1);
      if (sc > best) { best = sc; bi = v; }
    }
  }
#pragma unroll
  for (int o = 32; o > 0; o >>= 1) {
    const float t = __shfl_down(best, o);
    const int j = __shfl_down(bi, o);
    if (t > best || (t == best && j < bi)) { best = t; bi = j; }
  }
  const int w = tid >> 6;
  __syncthreads();
  if ((tid & 63) == 0) { redf[w] = best; redi[w] = bi; }
  __syncthreads();
  if (tid == 0) {
    float bs = redf[0];
    int bidx = redi[0];
    for (int k = 1; k < 16; k++)
      if (redf[k] > bs || (redf[k] == bs && redi[k] < bidx)) { bs = redf[k]; bidx = redi[k]; }
    out[b] = bidx;
  }
}

extern "C" void kernel_launch(void* const* d_in, const int* in_sizes, int n_in,
                              void* d_out, int out_size, void* d_ws, size_t ws_size,
                              hipStream_t stream) {
  (void)in_sizes; (void)n_in; (void)out_size; (void)ws_size;
  const float* A = (const float*)d_in[0];     // hidden_states [128,4096]
  const float* W = (const float*)d_in[1];     // embd_weight   [32000,4096]
  const float* temp = (const float*)d_in[2];  // temperature   [128]
  const float* topp = (const float*)d_in[3];  // top_p         [128]
  int* out = (int*)d_out;                     // ids           [128] int32

  char* base = (char*)d_ws;
  float* L = (float*)base;                                  // 16,384,000 B
  unsigned short* Asp = (unsigned short*)(base + (size_t)B_ * V_ * 4);  // 2,097,152 B

  asplit_kernel<<<dim3(256), dim3(256), 0, stream>>>(A, Asp);
  gemm_mfma<<<dim3(V_ / BN), dim3(256), 0, stream>>>(Asp, W, temp, L);
  sampler_kernel<<<dim3(B_), dim3(1024), 0, stream>>>(L, topp, out);
}